// Round 1
// baseline (8461.860 us; speedup 1.0000x reference)
//
#include <hip/hip_runtime.h>
#include <math.h>

#define BQ 8
#define PP 196
#define DD 2048
#define AA 700
#define HH 700
#define EE 700
#define VV 30000
#define NSTEP 30
#define G4 2800
#define XK 2748          // E + D
#define NVB 469          // ceil(VV/64)

__device__ __forceinline__ float sigm(float x) { return 1.f / (1.f + expf(-x)); }

// -------- prologue: mean over pixels --------
__global__ __launch_bounds__(256) void k_mean(const float* __restrict__ enc,
                                              float* __restrict__ mean) {
    int b = blockIdx.x >> 3;
    int d = ((blockIdx.x & 7) << 8) + threadIdx.x;
    const float* p = enc + (size_t)b * PP * DD + d;
    float s = 0.f;
    for (int i = 0; i < PP; i++) s += p[(size_t)i * DD];
    mean[b * DD + d] = s * (1.0f / PP);
}

// -------- prologue: h0 = mean@W_init_h + b ; c0 similarly (one launch) --------
__global__ __launch_bounds__(256) void k_init_hc(const float* __restrict__ mean,
    const float* __restrict__ Wh, const float* __restrict__ bh,
    const float* __restrict__ Wc, const float* __restrict__ bc,
    float* __restrict__ h, float* __restrict__ c) {
    __shared__ float X[BQ][DD];            // 64KB
    __shared__ float red[4][64][BQ];       // 8KB
    int tid = threadIdx.x;
    for (int i = tid; i < BQ * DD; i += 256) X[i / DD][i % DD] = mean[i];
    __syncthreads();
    int j = blockIdx.x * 64 + (tid & 63);
    int kq = tid >> 6;
    float acc[BQ];
    #pragma unroll
    for (int b = 0; b < BQ; b++) acc[b] = 0.f;
    if (j < 2 * HH) {
        bool isH = j < HH;
        int col = isH ? j : j - HH;
        const float* wp = (isH ? Wh : Wc) + (size_t)(kq * 512) * HH + col;
        for (int k = kq * 512; k < kq * 512 + 512; k++) {
            float wv = *wp; wp += HH;
            #pragma unroll
            for (int b = 0; b < BQ; b++) acc[b] += X[b][k] * wv;
        }
    }
    #pragma unroll
    for (int b = 0; b < BQ; b++) red[kq][tid & 63][b] = acc[b];
    __syncthreads();
    for (int idx = tid; idx < 512; idx += 256) {
        int jj = idx >> 3, b = idx & 7;
        int jg = blockIdx.x * 64 + jj;
        if (jg >= 2 * HH) continue;
        float s = red[0][jj][b] + red[1][jj][b] + red[2][jj][b] + red[3][jj][b];
        bool isH = jg < HH;
        int col = isH ? jg : jg - HH;
        s += isH ? bh[col] : bc[col];
        (isH ? h : c)[b * HH + col] = s;
    }
}

// -------- prologue: att1 = enc_flat(1568,2048) @ W_enc_att(2048,700) + b --------
__global__ __launch_bounds__(256) void k_att1(const float* __restrict__ Aenc,
    const float* __restrict__ W, const float* __restrict__ bias,
    float* __restrict__ att1) {
    const int M = BQ * PP; // 1568
    __shared__ float As[16][65];
    __shared__ float Bs[16][65];
    int bm = blockIdx.x, bn = blockIdx.y;
    int tid = threadIdx.x;
    int tx = tid & 15, ty = tid >> 4;
    float acc[4][4] = {};
    for (int kt = 0; kt < DD; kt += 16) {
        for (int i = tid; i < 1024; i += 256) {
            int r = i >> 4, ck = i & 15;
            int row = bm * 64 + r;
            As[ck][r] = (row < M) ? Aenc[(size_t)row * DD + kt + ck] : 0.f;
        }
        for (int i = tid; i < 1024; i += 256) {
            int rk = i >> 6, n = i & 63;
            int col = bn * 64 + n;
            Bs[rk][n] = (col < AA) ? W[(size_t)(kt + rk) * AA + col] : 0.f;
        }
        __syncthreads();
        #pragma unroll
        for (int k = 0; k < 16; k++) {
            float a[4], bb[4];
            #pragma unroll
            for (int i = 0; i < 4; i++) a[i] = As[k][ty * 4 + i];
            #pragma unroll
            for (int jx = 0; jx < 4; jx++) bb[jx] = Bs[k][tx * 4 + jx];
            #pragma unroll
            for (int i = 0; i < 4; i++)
                #pragma unroll
                for (int jx = 0; jx < 4; jx++) acc[i][jx] += a[i] * bb[jx];
        }
        __syncthreads();
    }
    for (int i = 0; i < 4; i++) {
        int row = bm * 64 + ty * 4 + i;
        if (row >= M) continue;
        for (int jx = 0; jx < 4; jx++) {
            int col = bn * 64 + tx * 4 + jx;
            if (col < AA) att1[(size_t)row * AA + col] = acc[i][jx] + bias[col];
        }
    }
}

// -------- step A: att2 / hWhh / gLin from h, plus prev-step argmax finalize --------
__global__ __launch_bounds__(256) void k_stepA(const float* __restrict__ h,
    const float* __restrict__ Wd,  const float* __restrict__ bd,
    const float* __restrict__ Whh, const float* __restrict__ bhh,
    const float* __restrict__ Wfb, const float* __restrict__ bfb,
    float* __restrict__ att2, float* __restrict__ hWhh, float* __restrict__ gLin,
    const float* __restrict__ argval, const int* __restrict__ argidx,
    int* __restrict__ prev, int t) {
    __shared__ float X[BQ][HH];
    __shared__ float red[4][64][BQ];
    int tid = threadIdx.x;
    if (blockIdx.x == 87) {   // argmax finalize for previous step
        int b = tid >> 5, l = tid & 31;
        if (b < BQ) {
            if (t == 0) {
                if (l == 0) prev[b] = 1;
            } else {
                float bv = -3.4e38f; int bi = 0x7fffffff;
                for (int vb = l; vb < NVB; vb += 32) {
                    float v = argval[vb * BQ + b];
                    int ix = argidx[vb * BQ + b];
                    if (v > bv || (v == bv && ix < bi)) { bv = v; bi = ix; }
                }
                for (int off = 16; off > 0; off >>= 1) {
                    float ov = __shfl_down(bv, off, 32);
                    int   oi = __shfl_down(bi, off, 32);
                    if (ov > bv || (ov == bv && oi < bi)) { bv = ov; bi = oi; }
                }
                if (l == 0) prev[b] = bi;
            }
        }
        return;
    }
    for (int i = tid; i < BQ * HH; i += 256) X[i / HH][i % HH] = h[i];
    __syncthreads();
    int j = blockIdx.x * 64 + (tid & 63);
    int kq = tid >> 6;
    float acc[BQ];
    #pragma unroll
    for (int b = 0; b < BQ; b++) acc[b] = 0.f;
    if (j < 5548) {
        const float* W; int col, stride;
        if (j < 700)       { W = Wd;  col = j;        stride = AA; }
        else if (j < 3500) { W = Whh; col = j - 700;  stride = G4; }
        else               { W = Wfb; col = j - 3500; stride = DD; }
        const float* wp = W + (size_t)(kq * 175) * stride + col;
        for (int k = 0; k < 175; k++) {
            float wv = *wp; wp += stride;
            int kk = kq * 175 + k;
            #pragma unroll
            for (int b = 0; b < BQ; b++) acc[b] += X[b][kk] * wv;
        }
    }
    #pragma unroll
    for (int b = 0; b < BQ; b++) red[kq][tid & 63][b] = acc[b];
    __syncthreads();
    for (int idx = tid; idx < 512; idx += 256) {
        int jj = idx >> 3, b = idx & 7;
        int jg = blockIdx.x * 64 + jj;
        if (jg >= 5548) continue;
        float s = red[0][jj][b] + red[1][jj][b] + red[2][jj][b] + red[3][jj][b];
        if (jg < 700)       att2[b * AA + jg]          = s + bd[jg];
        else if (jg < 3500) hWhh[b * G4 + (jg - 700)]  = s + bhh[jg - 700];
        else                gLin[b * DD + (jg - 3500)] = s + bfb[jg - 3500];
    }
}

// -------- step B: e = relu(att1+att2)@W_full, softmax -> alpha --------
__global__ __launch_bounds__(256) void k_stepB(const float* __restrict__ att1,
    const float* __restrict__ att2, const float* __restrict__ Wf,
    float* __restrict__ alpha, float* __restrict__ oalpha, int t) {
    int b = blockIdx.x;
    __shared__ float a2[AA];
    __shared__ float wf[AA];
    __shared__ float e[PP];
    __shared__ float rbuf[4];
    int tid = threadIdx.x;
    for (int i = tid; i < AA; i += 256) { a2[i] = att2[b * AA + i]; wf[i] = Wf[i]; }
    __syncthreads();
    int w = tid >> 6, l = tid & 63;
    for (int p = w; p < PP; p += 4) {
        const float* ap = att1 + (size_t)(b * PP + p) * AA;
        float s = 0.f;
        for (int a = l; a < AA; a += 64) {
            float v = ap[a] + a2[a];
            s += (v > 0.f ? v : 0.f) * wf[a];
        }
        for (int off = 32; off > 0; off >>= 1) s += __shfl_down(s, off);
        if (l == 0) e[p] = s;
    }
    __syncthreads();
    float v = (tid < PP) ? e[tid] : -3.4e38f;
    float m = v;
    for (int off = 32; off > 0; off >>= 1) m = fmaxf(m, __shfl_down(m, off));
    if (l == 0) rbuf[w] = m;
    __syncthreads();
    m = fmaxf(fmaxf(rbuf[0], rbuf[1]), fmaxf(rbuf[2], rbuf[3]));
    float ex = (tid < PP) ? expf(v - m) : 0.f;
    __syncthreads();
    float s2 = ex;
    for (int off = 32; off > 0; off >>= 1) s2 += __shfl_down(s2, off);
    if (l == 0) rbuf[w] = s2;
    __syncthreads();
    float den = rbuf[0] + rbuf[1] + rbuf[2] + rbuf[3];
    if (tid < PP) {
        float a = ex / den;
        alpha[b * PP + tid] = a;
        oalpha[((size_t)b * NSTEP + t) * PP + tid] = a;
    }
}

// -------- step C: awe = sigmoid(gLin) * (alpha @ enc) --------
__global__ __launch_bounds__(1024) void k_stepC(const float* __restrict__ enc,
    const float* __restrict__ alpha, const float* __restrict__ gLin,
    float* __restrict__ awe) {
    int b = blockIdx.x >> 3, dc = blockIdx.x & 7;
    __shared__ float al[PP];
    __shared__ float red[4][256];
    int tid = threadIdx.x;
    if (tid < PP) al[tid] = alpha[b * PP + tid];
    __syncthreads();
    int d = dc * 256 + (tid & 255);
    int pq = tid >> 8;
    const float* ep = enc + (size_t)(b * PP) * DD + d;
    float s = 0.f;
    for (int p = pq * 49; p < pq * 49 + 49; p++) s += al[p] * ep[(size_t)p * DD];
    red[pq][tid & 255] = s;
    __syncthreads();
    if (tid < 256) {
        float tot = red[0][tid] + red[1][tid] + red[2][tid] + red[3][tid];
        int dg = dc * 256 + tid;
        awe[b * DD + dg] = sigm(gLin[b * DD + dg]) * tot;
    }
}

// -------- step D1: gates partials = [emb[prev]; awe] @ W_ih (k-split) --------
__global__ __launch_bounds__(256) void k_stepD1(const float* __restrict__ emb,
    const int* __restrict__ prev, const float* __restrict__ awe,
    const float* __restrict__ Wih, float* __restrict__ part) {
    int jb = blockIdx.x >> 3, kc = blockIdx.x & 7;
    int tid = threadIdx.x;
    __shared__ float X[BQ][344];
    __shared__ float red[4][64][32];
    int k0 = kc * 344;
    int klen = XK - k0; if (klen > 344) klen = 344;
    for (int i = tid; i < BQ * 344; i += 256) {
        int b = i / 344, k = i - b * 344;
        int kg = k0 + k;
        float xv = 0.f;
        if (kg < XK) xv = (kg < EE) ? emb[(size_t)prev[b] * EE + kg]
                                    : awe[b * DD + (kg - EE)];
        X[b][k] = xv;
    }
    __syncthreads();
    int jj = tid & 63, kq = tid >> 6;
    int j = jb * 64 + jj;
    float acc[BQ][4] = {};
    if (j < HH) {
        int kend = kq * 86 + 86; if (kend > klen) kend = klen;
        for (int k = kq * 86; k < kend; k++) {
            const float* wr = Wih + (size_t)(k0 + k) * G4 + j;
            float w0 = wr[0], w1 = wr[700], w2 = wr[1400], w3 = wr[2100];
            #pragma unroll
            for (int b = 0; b < BQ; b++) {
                float x = X[b][k];
                acc[b][0] += x * w0; acc[b][1] += x * w1;
                acc[b][2] += x * w2; acc[b][3] += x * w3;
            }
        }
    }
    #pragma unroll
    for (int b = 0; b < BQ; b++)
        #pragma unroll
        for (int g = 0; g < 4; g++) red[kq][jj][g * 8 + b] = acc[b][g];
    __syncthreads();
    for (int idx = tid; idx < 64 * 32; idx += 256) {
        int jj2 = idx >> 5, gb = idx & 31;
        int j2 = jb * 64 + jj2;
        if (j2 < HH) {
            float s = red[0][jj2][gb] + red[1][jj2][gb] + red[2][jj2][gb] + red[3][jj2][gb];
            part[((size_t)kc * HH + j2) * 32 + gb] = s;
        }
    }
}

// -------- step D2: reduce partials + LSTM cell --------
__global__ __launch_bounds__(256) void k_stepD2(const float* __restrict__ part,
    const float* __restrict__ bih, const float* __restrict__ hWhh,
    float* __restrict__ c, float* __restrict__ h) {
    int idx = blockIdx.x * 256 + threadIdx.x;
    if (idx >= BQ * HH) return;
    int j = idx >> 3, b = idx & 7;
    float s[4];
    #pragma unroll
    for (int g = 0; g < 4; g++) s[g] = bih[g * HH + j] + hWhh[b * G4 + g * HH + j];
    for (int kc = 0; kc < 8; kc++) {
        const float* pp = part + ((size_t)kc * HH + j) * 32 + b;
        #pragma unroll
        for (int g = 0; g < 4; g++) s[g] += pp[g * 8];
    }
    float ig = sigm(s[0]), fg = sigm(s[1]), gg = tanhf(s[2]), og = sigm(s[3]);
    float cn = fg * c[b * HH + j] + ig * gg;
    c[b * HH + j] = cn;
    h[b * HH + j] = og * tanhf(cn);
}

// -------- step E: logits = h@W_fc + b_fc, write preds, per-block argmax --------
__global__ __launch_bounds__(256) void k_stepE(const float* __restrict__ h,
    const float* __restrict__ Wfc, const float* __restrict__ bfc,
    float* __restrict__ preds, float* __restrict__ argval, int* __restrict__ argidx,
    int t) {
    __shared__ float X[BQ][HH];
    __shared__ float red[4][64][BQ];
    __shared__ float lg[64][BQ];
    int tid = threadIdx.x;
    for (int i = tid; i < BQ * HH; i += 256) X[i / HH][i % HH] = h[i];
    __syncthreads();
    int v = blockIdx.x * 64 + (tid & 63);
    int kq = tid >> 6;
    float acc[BQ];
    #pragma unroll
    for (int b = 0; b < BQ; b++) acc[b] = 0.f;
    if (v < VV) {
        const float* wp = Wfc + (size_t)(kq * 175) * VV + v;
        for (int k = 0; k < 175; k++) {
            float wv = *wp; wp += VV;
            int kk = kq * 175 + k;
            #pragma unroll
            for (int b = 0; b < BQ; b++) acc[b] += X[b][kk] * wv;
        }
    }
    #pragma unroll
    for (int b = 0; b < BQ; b++) red[kq][tid & 63][b] = acc[b];
    __syncthreads();
    for (int idx = tid; idx < 512; idx += 256) {
        int jj = idx >> 3, b = idx & 7;
        int vg = blockIdx.x * 64 + jj;
        float s = -3.4e38f;
        if (vg < VV) {
            s = red[0][jj][b] + red[1][jj][b] + red[2][jj][b] + red[3][jj][b] + bfc[vg];
            preds[((size_t)b * NSTEP + t) * VV + vg] = s;
        }
        lg[jj][b] = s;
    }
    __syncthreads();
    if (tid < BQ) {
        int b = tid;
        float bv = lg[0][b]; int bi = blockIdx.x * 64;
        for (int i2 = 1; i2 < 64; i2++) {
            float vv = lg[i2][b];
            if (vv > bv) { bv = vv; bi = blockIdx.x * 64 + i2; }
        }
        argval[blockIdx.x * BQ + b] = bv;
        argidx[blockIdx.x * BQ + b] = bi;
    }
}

extern "C" void kernel_launch(void* const* d_in, const int* in_sizes, int n_in,
                              void* d_out, int out_size, void* d_ws, size_t ws_size,
                              hipStream_t stream) {
    (void)in_sizes; (void)n_in; (void)out_size; (void)ws_size;
    const float* enc   = (const float*)d_in[0];
    // d_in[1] = encoded_captions (only defines T; unused)
    const float* emb   = (const float*)d_in[2];
    const float* Wea   = (const float*)d_in[3];
    const float* bea   = (const float*)d_in[4];
    const float* Wda   = (const float*)d_in[5];
    const float* bda   = (const float*)d_in[6];
    const float* Wfull = (const float*)d_in[7];
    // d_in[8] = b_full (softmax-invariant, unused)
    const float* Wih   = (const float*)d_in[9];
    const float* bih   = (const float*)d_in[10];
    const float* Whh   = (const float*)d_in[11];
    const float* bhh   = (const float*)d_in[12];
    const float* Winh  = (const float*)d_in[13];
    const float* binh  = (const float*)d_in[14];
    const float* Winc  = (const float*)d_in[15];
    const float* binc  = (const float*)d_in[16];
    const float* Wfb   = (const float*)d_in[17];
    const float* bfb   = (const float*)d_in[18];
    const float* Wfc   = (const float*)d_in[19];
    const float* bfc   = (const float*)d_in[20];

    float* preds  = (float*)d_out;
    float* oalpha = preds + (size_t)BQ * NSTEP * VV;

    float* w = (float*)d_ws;
    float* att1   = w; w += (size_t)BQ * PP * AA;   // 1,097,600
    float* mean   = w; w += BQ * DD;                // 16,384
    float* hbuf   = w; w += BQ * HH;
    float* cbuf   = w; w += BQ * HH;
    float* att2   = w; w += BQ * AA;
    float* hWhh   = w; w += BQ * G4;
    float* gLin   = w; w += BQ * DD;
    float* alpha  = w; w += BQ * PP;
    float* awe    = w; w += BQ * DD;
    float* part   = w; w += (size_t)8 * HH * 32;    // 179,200
    float* argval = w; w += NVB * BQ;
    int*   argidx = (int*)w; w += NVB * BQ;
    int*   prev   = (int*)w;

    k_mean<<<64, 256, 0, stream>>>(enc, mean);
    k_init_hc<<<22, 256, 0, stream>>>(mean, Winh, binh, Winc, binc, hbuf, cbuf);
    k_att1<<<dim3(25, 11), 256, 0, stream>>>(enc, Wea, bea, att1);

    for (int t = 0; t < NSTEP; t++) {
        k_stepA<<<88, 256, 0, stream>>>(hbuf, Wda, bda, Whh, bhh, Wfb, bfb,
                                        att2, hWhh, gLin, argval, argidx, prev, t);
        k_stepB<<<8, 256, 0, stream>>>(att1, att2, Wfull, alpha, oalpha, t);
        k_stepC<<<64, 1024, 0, stream>>>(enc, alpha, gLin, awe);
        k_stepD1<<<88, 256, 0, stream>>>(emb, prev, awe, Wih, part);
        k_stepD2<<<22, 256, 0, stream>>>(part, bih, hWhh, cbuf, hbuf);
        k_stepE<<<NVB, 256, 0, stream>>>(hbuf, Wfc, bfc, preds, argval, argidx, t);
    }
}

// Round 2
// 6962.241 us; speedup vs baseline: 1.2154x; 1.2154x over previous
//
#include <hip/hip_runtime.h>
#include <math.h>

#define BQ 8
#define PP 196
#define DD 2048
#define AA 700
#define HH 700
#define EE 700
#define VV 30000
#define NSTEP 30
#define G4 2800
#define NA 2748    // A cols: att2(700) + gLin(2048)
#define KD 3448    // D1 virtual K: emb(700) + awe(2048) + h(700)
#define KSA 16
#define KSD 24
#define KSE 4
#define NCBA 11
#define NCBD 11
#define NCBE 118
#define NB2 235    // E2 argmax partial blocks

__device__ __forceinline__ float sigm(float x) { return 1.f / (1.f + expf(-x)); }

// -------- prologue: mean over pixels --------
__global__ __launch_bounds__(256) void k_mean(const float* __restrict__ enc,
                                              float* __restrict__ mean) {
    int b = blockIdx.x >> 3;
    int d = ((blockIdx.x & 7) << 8) + threadIdx.x;
    const float* p = enc + (size_t)b * PP * DD + d;
    float s = 0.f;
    for (int i = 0; i < PP; i++) s += p[(size_t)i * DD];
    mean[b * DD + d] = s * (1.0f / PP);
}

// -------- prologue: h0 / c0 --------
__global__ __launch_bounds__(256) void k_init_hc(const float* __restrict__ mean,
    const float* __restrict__ Wh, const float* __restrict__ bh,
    const float* __restrict__ Wc, const float* __restrict__ bc,
    float* __restrict__ h, float* __restrict__ c) {
    __shared__ float X[BQ][DD];
    __shared__ float red[4][64][BQ];
    int tid = threadIdx.x;
    for (int i = tid; i < BQ * DD; i += 256) X[i / DD][i % DD] = mean[i];
    __syncthreads();
    int j = blockIdx.x * 64 + (tid & 63);
    int kq = tid >> 6;
    float acc[BQ];
    #pragma unroll
    for (int b = 0; b < BQ; b++) acc[b] = 0.f;
    if (j < 2 * HH) {
        bool isH = j < HH;
        int col = isH ? j : j - HH;
        const float* wp = (isH ? Wh : Wc) + (size_t)(kq * 512) * HH + col;
        for (int k = kq * 512; k < kq * 512 + 512; k++) {
            float wv = *wp; wp += HH;
            #pragma unroll
            for (int b = 0; b < BQ; b++) acc[b] += X[b][k] * wv;
        }
    }
    #pragma unroll
    for (int b = 0; b < BQ; b++) red[kq][tid & 63][b] = acc[b];
    __syncthreads();
    for (int idx = tid; idx < 512; idx += 256) {
        int jj = idx >> 3, b = idx & 7;
        int jg = blockIdx.x * 64 + jj;
        if (jg >= 2 * HH) continue;
        float s = red[0][jj][b] + red[1][jj][b] + red[2][jj][b] + red[3][jj][b];
        bool isH = jg < HH;
        int col = isH ? jg : jg - HH;
        s += isH ? bh[col] : bc[col];
        (isH ? h : c)[b * HH + col] = s;
    }
}

// -------- prologue: att1 = enc_flat @ W_enc_att + b (conflict-free float4 tiles) ----
__global__ __launch_bounds__(256) void k_att1(const float* __restrict__ Aenc,
    const float* __restrict__ W, const float* __restrict__ bias,
    float* __restrict__ att1) {
    const int M = BQ * PP; // 1568
    __shared__ float As[16][68];
    __shared__ float Bs[16][68];
    int bm = blockIdx.x, bn = blockIdx.y;
    int tid = threadIdx.x;
    int tx = tid & 15, ty = tid >> 4;
    float acc[4][4] = {};
    for (int kt = 0; kt < DD; kt += 16) {
        {
            int row = tid >> 2, k4 = (tid & 3) * 4;
            int grow = bm * 64 + row;
            float4 v = make_float4(0.f, 0.f, 0.f, 0.f);
            if (grow < M) v = *(const float4*)&Aenc[(size_t)grow * DD + kt + k4];
            As[k4 + 0][row] = v.x; As[k4 + 1][row] = v.y;
            As[k4 + 2][row] = v.z; As[k4 + 3][row] = v.w;
        }
        {
            int rk = tid >> 4, n4 = (tid & 15) * 4;
            int col = bn * 64 + n4;
            float4 wv = make_float4(0.f, 0.f, 0.f, 0.f);
            if (col < AA) wv = *(const float4*)&W[(size_t)(kt + rk) * AA + col];
            *(float4*)&Bs[rk][n4] = wv;
        }
        __syncthreads();
        #pragma unroll
        for (int k = 0; k < 16; k++) {
            float4 a  = *(const float4*)&As[k][ty * 4];
            float4 bv = *(const float4*)&Bs[k][tx * 4];
            float av[4] = {a.x, a.y, a.z, a.w};
            float bb[4] = {bv.x, bv.y, bv.z, bv.w};
            #pragma unroll
            for (int i = 0; i < 4; i++)
                #pragma unroll
                for (int j = 0; j < 4; j++) acc[i][j] += av[i] * bb[j];
        }
        __syncthreads();
    }
    for (int i = 0; i < 4; i++) {
        int row = bm * 64 + ty * 4 + i;
        if (row >= M) continue;
        for (int j = 0; j < 4; j++) {
            int col = bn * 64 + tx * 4 + j;
            if (col < AA) att1[(size_t)row * AA + col] = acc[i][j] + bias[col];
        }
    }
}

// -------- step A: pA[kc][col][b] partials of h @ [W_dec_att | W_fbeta] --------
__global__ __launch_bounds__(256) void k_stepA(const float* __restrict__ h,
    const float* __restrict__ Wda, const float* __restrict__ Wfb,
    float* __restrict__ pA) {
    int cb = blockIdx.x % NCBA, kc = blockIdx.x / NCBA;
    int k0 = (kc * AA) / KSA, k1 = ((kc + 1) * AA) / KSA;
    int KR = k1 - k0;
    __shared__ float X[44][8];
    __shared__ float red[4 * 64 * 36];
    int tid = threadIdx.x;
    for (int i = tid; i < KR * 8; i += 256) {
        int k = i >> 3, b = i & 7;
        X[k][b] = h[b * HH + k0 + k];
    }
    __syncthreads();
    int lane = tid & 63, kq = tid >> 6;
    int ka = (kq * KR) >> 2, kb = ((kq + 1) * KR) >> 2;
    int c0 = cb * 256 + lane * 4;
    float acc[8][4] = {};
    if (c0 < NA) {
        const float* W; int col, stride;
        if (c0 < AA) { W = Wda; col = c0;      stride = AA; }
        else         { W = Wfb; col = c0 - AA; stride = DD; }
        const float* wp = W + (size_t)(k0 + ka) * stride + col;
        #pragma unroll 2
        for (int k = ka; k < kb; ++k) {
            float4 wv = *(const float4*)wp; wp += stride;
            float4 xa = *(const float4*)&X[k][0];
            float4 xb = *(const float4*)&X[k][4];
            float w4[4] = {wv.x, wv.y, wv.z, wv.w};
            float xv[8] = {xa.x, xa.y, xa.z, xa.w, xb.x, xb.y, xb.z, xb.w};
            #pragma unroll
            for (int b = 0; b < 8; b++)
                #pragma unroll
                for (int cc = 0; cc < 4; cc++) acc[b][cc] += xv[b] * w4[cc];
        }
    }
    float* rr = &red[(kq * 64 + lane) * 36];
    #pragma unroll
    for (int b = 0; b < 8; b++)
        #pragma unroll
        for (int cc = 0; cc < 4; cc++) rr[cc * 8 + b] = acc[b][cc];
    __syncthreads();
    for (int idx = tid; idx < 2048; idx += 256) {
        int cl = idx >> 3, b = idx & 7;
        int gc = cb * 256 + cl;
        if (gc >= NA) continue;
        int ln = cl >> 2, cc = cl & 3;
        float s = 0.f;
        #pragma unroll
        for (int q = 0; q < 4; q++) s += red[(q * 64 + ln) * 36 + cc * 8 + b];
        pA[((size_t)kc * NA + gc) * 8 + b] = s;
    }
}

// -------- step B: att2 reduce + e = relu(att1+att2)@W_full + softmax --------
__global__ __launch_bounds__(256) void k_stepB(const float* __restrict__ pA,
    const float* __restrict__ bda, const float* __restrict__ att1,
    const float* __restrict__ Wf, float* __restrict__ alpha,
    float* __restrict__ oalpha, int t) {
    int b = blockIdx.x;
    __shared__ float a2[AA];
    __shared__ float wf[AA];
    __shared__ float e[PP];
    __shared__ float rbuf[4];
    int tid = threadIdx.x;
    for (int i = tid; i < AA; i += 256) {
        float s = bda[i];
        for (int kc = 0; kc < KSA; kc++) s += pA[((size_t)kc * NA + i) * 8 + b];
        a2[i] = s;
        wf[i] = Wf[i];
    }
    __syncthreads();
    int w = tid >> 6, l = tid & 63;
    for (int p = w; p < PP; p += 4) {
        const float* ap = att1 + (size_t)(b * PP + p) * AA;
        float s = 0.f;
        for (int a = l; a < AA; a += 64) {
            float v = ap[a] + a2[a];
            s += (v > 0.f ? v : 0.f) * wf[a];
        }
        for (int off = 32; off > 0; off >>= 1) s += __shfl_down(s, off);
        if (l == 0) e[p] = s;
    }
    __syncthreads();
    float v = (tid < PP) ? e[tid] : -3.4e38f;
    float m = v;
    for (int off = 32; off > 0; off >>= 1) m = fmaxf(m, __shfl_down(m, off));
    if (l == 0) rbuf[w] = m;
    __syncthreads();
    m = fmaxf(fmaxf(rbuf[0], rbuf[1]), fmaxf(rbuf[2], rbuf[3]));
    float ex = (tid < PP) ? expf(v - m) : 0.f;
    __syncthreads();
    float s2 = ex;
    for (int off = 32; off > 0; off >>= 1) s2 += __shfl_down(s2, off);
    if (l == 0) rbuf[w] = s2;
    __syncthreads();
    float den = rbuf[0] + rbuf[1] + rbuf[2] + rbuf[3];
    if (tid < PP) {
        float a = ex / den;
        alpha[b * PP + tid] = a;
        oalpha[((size_t)b * NSTEP + t) * PP + tid] = a;
    }
}

// -------- step C: awe = sigmoid(gLin) * (alpha @ enc)  (gLin from pA) --------
__global__ __launch_bounds__(256) void k_stepC(const float* __restrict__ enc,
    const float* __restrict__ pA, const float* __restrict__ bfb,
    const float* __restrict__ alpha, float* __restrict__ awe) {
    int b = blockIdx.x >> 5, dc = blockIdx.x & 31;
    __shared__ float al[PP];
    __shared__ float gsh[64];
    __shared__ float red2[4][64];
    int tid = threadIdx.x;
    if (tid < 64) {
        int d = dc * 64 + tid;
        float s = bfb[d];
        for (int kc = 0; kc < KSA; kc++) s += pA[((size_t)kc * NA + AA + d) * 8 + b];
        gsh[tid] = sigm(s);
    }
    for (int i = tid; i < PP; i += 256) al[i] = alpha[b * PP + i];
    __syncthreads();
    int lane = tid & 63, w = tid >> 6;
    int d = dc * 64 + lane;
    const float* ep = enc + ((size_t)b * PP) * DD + d;
    float s = 0.f;
    for (int p = w * 49; p < w * 49 + 49; p++) s += al[p] * ep[(size_t)p * DD];
    red2[w][lane] = s;
    __syncthreads();
    if (tid < 64) {
        float tot = red2[0][tid] + red2[1][tid] + red2[2][tid] + red2[3][tid];
        awe[b * DD + dc * 64 + tid] = gsh[tid] * tot;
    }
}

// -------- step D1: argmax finalize + pD partials of [emb;awe;h] @ [W_ih;W_hh] ----
__global__ __launch_bounds__(256) void k_stepD1(const float* __restrict__ emb,
    const float* __restrict__ awe, const float* __restrict__ h,
    const float* __restrict__ Wih, const float* __restrict__ Whh,
    const float* __restrict__ argval, const int* __restrict__ argidx,
    float* __restrict__ pD, int t) {
    int cb = blockIdx.x % NCBD, kc = blockIdx.x / NCBD;
    int k0 = (kc * KD) / KSD, k1 = ((kc + 1) * KD) / KSD;
    int KR = k1 - k0;
    __shared__ float X[144][8];
    __shared__ float red[4 * 64 * 36];
    __shared__ int sprev[8];
    int tid = threadIdx.x;
    {
        int b = tid >> 5, l = tid & 31;
        if (b < 8) {
            if (t == 0) {
                if (l == 0) sprev[b] = 1;
            } else {
                float bv = -3.4e38f; int bi = 0x7fffffff;
                for (int vb = l; vb < NB2; vb += 32) {
                    float vv = argval[vb * 8 + b]; int ix = argidx[vb * 8 + b];
                    if (vv > bv || (vv == bv && ix < bi)) { bv = vv; bi = ix; }
                }
                #pragma unroll
                for (int off = 16; off > 0; off >>= 1) {
                    float ov = __shfl_down(bv, off, 32);
                    int   oi = __shfl_down(bi, off, 32);
                    if (ov > bv || (ov == bv && oi < bi)) { bv = ov; bi = oi; }
                }
                if (l == 0) sprev[b] = bi;
            }
        }
    }
    __syncthreads();
    for (int i = tid; i < KR * 8; i += 256) {
        int k = i >> 3, b = i & 7;
        int kg = k0 + k;
        float x;
        if (kg < EE)            x = emb[(size_t)sprev[b] * EE + kg];
        else if (kg < EE + DD)  x = awe[b * DD + (kg - EE)];
        else                    x = h[b * HH + (kg - EE - DD)];
        X[k][b] = x;
    }
    __syncthreads();
    int lane = tid & 63, kq = tid >> 6;
    int ka = (kq * KR) >> 2, kb2 = ((kq + 1) * KR) >> 2;
    int c0 = cb * 256 + lane * 4;
    float acc[8][4] = {};
    if (c0 < G4) {
        int kga = k0 + ka, kgb = k0 + kb2;
        #pragma unroll
        for (int seg = 0; seg < 2; seg++) {
            int sa = (seg == 0) ? kga : (kga > 2748 ? kga : 2748);
            int sb = (seg == 0) ? (kgb < 2748 ? kgb : 2748) : kgb;
            if (sa >= sb) continue;
            const float* wp = (seg == 0 ? Wih + (size_t)sa * G4
                                        : Whh + (size_t)(sa - 2748) * G4) + c0;
            #pragma unroll 2
            for (int kg = sa; kg < sb; ++kg) {
                int k = kg - k0;
                float4 wv = *(const float4*)wp; wp += G4;
                float4 xa = *(const float4*)&X[k][0];
                float4 xb = *(const float4*)&X[k][4];
                float w4[4] = {wv.x, wv.y, wv.z, wv.w};
                float xv[8] = {xa.x, xa.y, xa.z, xa.w, xb.x, xb.y, xb.z, xb.w};
                #pragma unroll
                for (int b = 0; b < 8; b++)
                    #pragma unroll
                    for (int cc = 0; cc < 4; cc++) acc[b][cc] += xv[b] * w4[cc];
            }
        }
    }
    float* rr = &red[(kq * 64 + lane) * 36];
    #pragma unroll
    for (int b = 0; b < 8; b++)
        #pragma unroll
        for (int cc = 0; cc < 4; cc++) rr[cc * 8 + b] = acc[b][cc];
    __syncthreads();
    for (int idx = tid; idx < 2048; idx += 256) {
        int cl = idx >> 3, b = idx & 7;
        int gc = cb * 256 + cl;
        if (gc >= G4) continue;
        int ln = cl >> 2, cc = cl & 3;
        float s = 0.f;
        #pragma unroll
        for (int q = 0; q < 4; q++) s += red[(q * 64 + ln) * 36 + cc * 8 + b];
        pD[((size_t)kc * G4 + gc) * 8 + b] = s;
    }
}

// -------- step D2: reduce pD + biases, LSTM cell --------
__global__ __launch_bounds__(256) void k_stepD2(const float* __restrict__ pD,
    const float* __restrict__ bih, const float* __restrict__ bhh,
    float* __restrict__ c, float* __restrict__ h) {
    int idx = blockIdx.x * 256 + threadIdx.x;
    if (idx >= BQ * HH) return;
    int j = idx >> 3, b = idx & 7;
    float s0 = bih[j]            + bhh[j];
    float s1 = bih[HH + j]       + bhh[HH + j];
    float s2 = bih[2 * HH + j]   + bhh[2 * HH + j];
    float s3 = bih[3 * HH + j]   + bhh[3 * HH + j];
    for (int kc = 0; kc < KSD; kc++) {
        const float* base = pD + (size_t)kc * G4 * 8;
        s0 += base[(j) * 8 + b];
        s1 += base[(HH + j) * 8 + b];
        s2 += base[(2 * HH + j) * 8 + b];
        s3 += base[(3 * HH + j) * 8 + b];
    }
    float ig = sigm(s0), fg = sigm(s1), gg = tanhf(s2), og = sigm(s3);
    float cn = fg * c[b * HH + j] + ig * gg;
    c[b * HH + j] = cn;
    h[b * HH + j] = og * tanhf(cn);
}

// -------- step E1: pE partials of h @ W_fc --------
__global__ __launch_bounds__(256) void k_stepE1(const float* __restrict__ h,
    const float* __restrict__ Wfc, float* __restrict__ pE) {
    int cb = blockIdx.x % NCBE, kc = blockIdx.x / NCBE;
    int k0 = kc * 175;
    __shared__ float X[175][8];
    __shared__ float red[4 * 64 * 36];
    int tid = threadIdx.x;
    for (int i = tid; i < 175 * 8; i += 256) {
        int k = i >> 3, b = i & 7;
        X[k][b] = h[b * HH + k0 + k];
    }
    __syncthreads();
    int lane = tid & 63, kq = tid >> 6;
    int ka = (kq * 175) >> 2, kb = ((kq + 1) * 175) >> 2;
    int c0 = cb * 256 + lane * 4;
    float acc[8][4] = {};
    if (c0 < VV) {
        const float* wp = Wfc + (size_t)(k0 + ka) * VV + c0;
        #pragma unroll 2
        for (int k = ka; k < kb; ++k) {
            float4 wv = *(const float4*)wp; wp += VV;
            float4 xa = *(const float4*)&X[k][0];
            float4 xb = *(const float4*)&X[k][4];
            float w4[4] = {wv.x, wv.y, wv.z, wv.w};
            float xv[8] = {xa.x, xa.y, xa.z, xa.w, xb.x, xb.y, xb.z, xb.w};
            #pragma unroll
            for (int b = 0; b < 8; b++)
                #pragma unroll
                for (int cc = 0; cc < 4; cc++) acc[b][cc] += xv[b] * w4[cc];
        }
    }
    float* rr = &red[(kq * 64 + lane) * 36];
    #pragma unroll
    for (int b = 0; b < 8; b++)
        #pragma unroll
        for (int cc = 0; cc < 4; cc++) rr[cc * 8 + b] = acc[b][cc];
    __syncthreads();
    for (int idx = tid; idx < 2048; idx += 256) {
        int cl = idx >> 3, b = idx & 7;
        int gc = cb * 256 + cl;
        if (gc >= VV) continue;
        int ln = cl >> 2, cc = cl & 3;
        float s = 0.f;
        #pragma unroll
        for (int q = 0; q < 4; q++) s += red[(q * 64 + ln) * 36 + cc * 8 + b];
        pE[((size_t)kc * VV + gc) * 8 + b] = s;
    }
}

// -------- step E2: reduce pE + b_fc, write preds, per-block argmax --------
__global__ __launch_bounds__(256) void k_stepE2(const float* __restrict__ pE,
    const float* __restrict__ bfc, float* __restrict__ preds,
    float* __restrict__ argval, int* __restrict__ argidx, int t) {
    __shared__ float lg[128][8];
    int tid = threadIdx.x;
    int base = blockIdx.x * 128;
    for (int idx = tid; idx < 1024; idx += 256) {
        int b = idx >> 7, cl = idx & 127;
        int col = base + cl;
        float s = -3.4e38f;
        if (col < VV) {
            s = bfc[col];
            #pragma unroll
            for (int kc = 0; kc < KSE; kc++) s += pE[((size_t)kc * VV + col) * 8 + b];
            preds[((size_t)b * NSTEP + t) * VV + col] = s;
        }
        lg[cl][b] = s;
    }
    __syncthreads();
    int b = tid >> 5, l = tid & 31;
    float bv = -3.4e38f; int bi = 0x7fffffff;
    for (int cl = l; cl < 128; cl += 32) {
        float v = lg[cl][b];
        int gi = base + cl;
        if (v > bv || (v == bv && gi < bi)) { bv = v; bi = gi; }
    }
    #pragma unroll
    for (int off = 16; off > 0; off >>= 1) {
        float ov = __shfl_down(bv, off, 32);
        int   oi = __shfl_down(bi, off, 32);
        if (ov > bv || (ov == bv && oi < bi)) { bv = ov; bi = oi; }
    }
    if (l == 0) { argval[blockIdx.x * 8 + b] = bv; argidx[blockIdx.x * 8 + b] = bi; }
}

extern "C" void kernel_launch(void* const* d_in, const int* in_sizes, int n_in,
                              void* d_out, int out_size, void* d_ws, size_t ws_size,
                              hipStream_t stream) {
    (void)in_sizes; (void)n_in; (void)out_size; (void)ws_size;
    const float* enc   = (const float*)d_in[0];
    const float* emb   = (const float*)d_in[2];
    const float* Wea   = (const float*)d_in[3];
    const float* bea   = (const float*)d_in[4];
    const float* Wda   = (const float*)d_in[5];
    const float* bda   = (const float*)d_in[6];
    const float* Wfull = (const float*)d_in[7];
    // d_in[8] = b_full (softmax-invariant, unused)
    const float* Wih   = (const float*)d_in[9];
    const float* bih   = (const float*)d_in[10];
    const float* Whh   = (const float*)d_in[11];
    const float* bhh   = (const float*)d_in[12];
    const float* Winh  = (const float*)d_in[13];
    const float* binh  = (const float*)d_in[14];
    const float* Winc  = (const float*)d_in[15];
    const float* binc  = (const float*)d_in[16];
    const float* Wfb   = (const float*)d_in[17];
    const float* bfb   = (const float*)d_in[18];
    const float* Wfc   = (const float*)d_in[19];
    const float* bfc   = (const float*)d_in[20];

    float* preds  = (float*)d_out;
    float* oalpha = preds + (size_t)BQ * NSTEP * VV;

    float* w = (float*)d_ws;
    float* att1   = w; w += (size_t)BQ * PP * AA;          // 1,097,600
    float* pA     = w; w += (size_t)KSA * NA * 8;          //   351,744
    float* pD     = w; w += (size_t)KSD * G4 * 8;          //   537,600
    float* pE     = w; w += (size_t)KSE * VV * 8;          //   960,000
    float* mean   = w; w += BQ * DD;
    float* hbuf   = w; w += BQ * HH;
    float* cbuf   = w; w += BQ * HH;
    float* alpha  = w; w += BQ * PP;
    float* awe    = w; w += BQ * DD;
    float* argval = w; w += NB2 * 8;
    int*   argidx = (int*)w; w += NB2 * 8;
    (void)ws_size;

    k_mean<<<64, 256, 0, stream>>>(enc, mean);
    k_init_hc<<<22, 256, 0, stream>>>(mean, Winh, binh, Winc, binc, hbuf, cbuf);
    k_att1<<<dim3(25, 11), 256, 0, stream>>>(enc, Wea, bea, att1);

    for (int t = 0; t < NSTEP; t++) {
        k_stepA<<<NCBA * KSA, 256, 0, stream>>>(hbuf, Wda, Wfb, pA);
        k_stepB<<<8, 256, 0, stream>>>(pA, bda, att1, Wfull, alpha, oalpha, t);
        k_stepC<<<256, 256, 0, stream>>>(enc, pA, bfb, alpha, awe);
        k_stepD1<<<NCBD * KSD, 256, 0, stream>>>(emb, awe, hbuf, Wih, Whh,
                                                 argval, argidx, pD, t);
        k_stepD2<<<22, 256, 0, stream>>>(pD, bih, bhh, cbuf, hbuf);
        k_stepE1<<<NCBE * KSE, 256, 0, stream>>>(hbuf, Wfc, pE);
        k_stepE2<<<NB2, 256, 0, stream>>>(pE, bfc, preds, argval, argidx, t);
    }
}